// Round 4
// baseline (777.999 us; speedup 1.0000x reference)
//
#include <hip/hip_runtime.h>

constexpr int NN  = 50000;   // nodes
constexpr int NE  = 800000;  // edges
constexpr int CIN = 128;     // input channels
constexpr int CH  = 256;     // hidden channels
constexpr int NG  = 512;     // graphs

typedef unsigned short ushort_t;
typedef unsigned int uint_t;

static __device__ __forceinline__ float bf2f(ushort_t u) {
    return __uint_as_float(((uint_t)u) << 16);
}
static __device__ __forceinline__ ushort_t f2bf(float f) {
    uint_t u = __float_as_uint(f);
    u += 0x7fffu + ((u >> 16) & 1u);   // round-to-nearest-even
    return (ushort_t)(u >> 16);
}
// accumulate 8 bf16 lanes of a uint4 with weight w
static __device__ __forceinline__ void acc8(float* acc, uint4 rv, float w) {
    acc[0] += w * __uint_as_float(rv.x << 16);
    acc[1] += w * __uint_as_float(rv.x & 0xffff0000u);
    acc[2] += w * __uint_as_float(rv.y << 16);
    acc[3] += w * __uint_as_float(rv.y & 0xffff0000u);
    acc[4] += w * __uint_as_float(rv.z << 16);
    acc[5] += w * __uint_as_float(rv.z & 0xffff0000u);
    acc[6] += w * __uint_as_float(rv.w << 16);
    acc[7] += w * __uint_as_float(rv.w & 0xffff0000u);
}

// ================= prep: fp32 -> bf16 converts =================
__global__ void conv_x_kernel(const float4* __restrict__ x, ushort4* __restrict__ xb, int n4) {
    int i = blockIdx.x * blockDim.x + threadIdx.x;
    if (i >= n4) return;
    float4 v = x[i];
    ushort4 o;
    o.x = f2bf(v.x); o.y = f2bf(v.y); o.z = f2bf(v.z); o.w = f2bf(v.w);
    xb[i] = o;
}

// Wt[n*K + k] = bf16(W[k*N + n])
__global__ void conv_wt_kernel(const float* __restrict__ W, ushort_t* __restrict__ Wt, int K, int N) {
    int i = blockIdx.x * blockDim.x + threadIdx.x;
    if (i >= K * N) return;
    int k = i / N, n = i % N;
    Wt[(size_t)n * K + k] = f2bf(W[i]);
}

// ================= CSR build =================
__global__ void count_kernel(const int* __restrict__ dst, int* __restrict__ cnt, int E) {
    int e = blockIdx.x * blockDim.x + threadIdx.x;
    if (e < E) atomicAdd(&cnt[dst[e]], 1);
}

// hierarchical scan, 3 kernels (256 items per block)
__global__ __launch_bounds__(256) void scan_bsum_kernel(const int* __restrict__ cnt,
                                                        int* __restrict__ bsum, int n) {
    int i = blockIdx.x * 256 + threadIdx.x;
    int v = (i < n) ? cnt[i] : 0;
    #pragma unroll
    for (int off = 32; off >= 1; off >>= 1) v += __shfl_xor(v, off, 64);
    __shared__ int ws[4];
    if ((threadIdx.x & 63) == 0) ws[threadIdx.x >> 6] = v;
    __syncthreads();
    if (threadIdx.x == 0) bsum[blockIdx.x] = ws[0] + ws[1] + ws[2] + ws[3];
}

// exclusive scan of nb (<=256) block sums in place, single block
__global__ __launch_bounds__(256) void scan_boff_kernel(int* __restrict__ bsum, int nb) {
    int tid = threadIdx.x, lane = tid & 63, wid = tid >> 6;
    int v = (tid < nb) ? bsum[tid] : 0;
    int s = v;
    #pragma unroll
    for (int off = 1; off < 64; off <<= 1) {
        int t = __shfl_up(s, off, 64);
        if (lane >= off) s += t;
    }
    __shared__ int wsum[4];
    if (lane == 63) wsum[wid] = s;
    __syncthreads();
    int wadd = 0;
    #pragma unroll
    for (int w = 0; w < 4; w++) if (w < wid) wadd += wsum[w];
    if (tid < nb) bsum[tid] = wadd + s - v;   // exclusive
}

__global__ __launch_bounds__(256) void scan_final_kernel(const int* __restrict__ cnt,
                                                         const int* __restrict__ boff,
                                                         int* __restrict__ rowptr,
                                                         float* __restrict__ dinv, int n) {
    int tid = threadIdx.x, lane = tid & 63, wid = tid >> 6;
    int i = blockIdx.x * 256 + tid;
    int v = (i < n) ? cnt[i] : 0;
    int s = v;
    #pragma unroll
    for (int off = 1; off < 64; off <<= 1) {
        int t = __shfl_up(s, off, 64);
        if (lane >= off) s += t;
    }
    __shared__ int wsum[4];
    if (lane == 63) wsum[wid] = s;
    __syncthreads();
    int wadd = boff[blockIdx.x];
    #pragma unroll
    for (int w = 0; w < 4; w++) if (w < wid) wadd += wsum[w];
    if (i < n) {
        rowptr[i] = wadd + s - v;
        dinv[i]   = rsqrtf((float)v + 1.0f);   // +1 self loop
        if (i == n - 1) rowptr[n] = wadd + s;
    }
}

__global__ void scatter_kernel(const int* __restrict__ src, const int* __restrict__ dst,
                               const int* __restrict__ rowptr, int* __restrict__ cursor,
                               int* __restrict__ col, int E) {
    int e = blockIdx.x * blockDim.x + threadIdx.x;
    if (e >= E) return;
    int d = dst[e];
    int p = rowptr[d] + atomicAdd(&cursor[d], 1);
    col[p] = src[e];
}

// ================= per-node gather aggregation (bf16, multi-node waves) ====
// NPW nodes per wave, LPN = 64/NPW lanes per node, 8 bf16 (16B) per lane.
// MODE 0: out(bf16) = dd*sum + dd^2*self
// MODE 1: out(bf16) = relu(dd*sum + dd^2*self + bias)
// MODE 2: atomicAdd relu(...) into fp32 out[batch[d]]
template <int C, int MODE, int NPW>
__global__ __launch_bounds__(256) void node_agg_kernel(
    const ushort_t* __restrict__ h, const int* __restrict__ rowptr,
    const int* __restrict__ col, const float* __restrict__ dinv,
    const float* __restrict__ bias, const int* __restrict__ batch,
    void* __restrict__ out_v, int n) {
    constexpr int LPN = 64 / NPW;
    static_assert(C / LPN == 8, "16B per lane");
    int wave = threadIdx.x >> 6;
    int lane = threadIdx.x & 63;
    int sub  = lane / LPN;
    int sl   = lane % LPN;
    int d = (blockIdx.x * 4 + wave) * NPW + sub;
    bool valid = d < n;
    int dc = valid ? d : (n - 1);

    int beg = rowptr[dc];
    int end = valid ? rowptr[dc + 1] : beg;

    float acc[8] = {};
    int e = beg;
    while (__any(e < end)) {
        int   si[4];
        float wi[4];
        #pragma unroll
        for (int u = 0; u < 4; u++) {
            int idx = e + u;
            bool a = idx < end;
            int ce = min(idx, NE - 1);      // always in-range load
            int sv = col[ce];
            int s = a ? sv : dc;            // fallback: self row (hot)
            si[u] = s;
            wi[u] = a ? dinv[s] : 0.0f;
        }
        #pragma unroll
        for (int u = 0; u < 4; u++) {
            uint4 rv = *(const uint4*)(h + (size_t)si[u] * C + sl * 8);
            acc8(acc, rv, wi[u]);
        }
        e += 4;
    }

    float dd = dinv[dc];
    float self[8];
    {
        uint4 sv = *(const uint4*)(h + (size_t)dc * C + sl * 8);
        self[0] = __uint_as_float(sv.x << 16);
        self[1] = __uint_as_float(sv.x & 0xffff0000u);
        self[2] = __uint_as_float(sv.y << 16);
        self[3] = __uint_as_float(sv.y & 0xffff0000u);
        self[4] = __uint_as_float(sv.z << 16);
        self[5] = __uint_as_float(sv.z & 0xffff0000u);
        self[6] = __uint_as_float(sv.w << 16);
        self[7] = __uint_as_float(sv.w & 0xffff0000u);
    }

    float r[8];
    if constexpr (MODE >= 1) {
        const float4* b4 = (const float4*)(bias + sl * 8);
        float4 blo = b4[0], bhi = b4[1];
        float bb[8] = {blo.x, blo.y, blo.z, blo.w, bhi.x, bhi.y, bhi.z, bhi.w};
        #pragma unroll
        for (int i = 0; i < 8; i++)
            r[i] = fmaxf(dd * acc[i] + dd * dd * self[i] + bb[i], 0.0f);
    } else {
        #pragma unroll
        for (int i = 0; i < 8; i++)
            r[i] = dd * acc[i] + dd * dd * self[i];
    }

    if constexpr (MODE == 2) {
        if (valid) {
            float* o = (float*)out_v + (size_t)batch[dc] * C + sl * 8;
            #pragma unroll
            for (int i = 0; i < 8; i++) atomicAdd(o + i, r[i]);
        }
    } else {
        if (valid) {
            uint4 o;
            o.x = (uint_t)f2bf(r[0]) | ((uint_t)f2bf(r[1]) << 16);
            o.y = (uint_t)f2bf(r[2]) | ((uint_t)f2bf(r[3]) << 16);
            o.z = (uint_t)f2bf(r[4]) | ((uint_t)f2bf(r[5]) << 16);
            o.w = (uint_t)f2bf(r[6]) | ((uint_t)f2bf(r[7]) << 16);
            *(uint4*)((ushort_t*)out_v + (size_t)dc * C + sl * 8) = o;
        }
    }
}

// ================= bf16 MFMA GEMM: C[M,256] = A[M,K] @ Wt[N,K]^T =================
typedef __attribute__((ext_vector_type(8))) short bf16x8;
typedef __attribute__((ext_vector_type(4))) float f32x4;

template <int MODE>
__global__ __launch_bounds__(256) void gemm_bf16_kernel(
    const ushort_t* __restrict__ A, const ushort_t* __restrict__ Wt,
    const float* __restrict__ bias, ushort_t* __restrict__ C, int M, int K) {
    __shared__ ushort_t As[128][40];
    __shared__ ushort_t Bs[128][40];
    int tid = threadIdx.x;
    int row0 = blockIdx.x * 128, col0 = blockIdx.y * 128;
    int lr = tid >> 2, lq = tid & 3;
    int lane = tid & 63, wv = tid >> 6;
    int wr = (wv >> 1) * 64, wc = (wv & 1) * 64;
    int r16 = lane & 15, quad = lane >> 4;

    f32x4 acc[4][4] = {};

    for (int k0 = 0; k0 < K; k0 += 32) {
        {
            int gr0 = row0 + lr, gr1 = row0 + lr + 64;
            uint4 a0 = make_uint4(0, 0, 0, 0), a1 = make_uint4(0, 0, 0, 0);
            if (gr0 < M) a0 = *(const uint4*)(A + (size_t)gr0 * K + k0 + lq * 8);
            if (gr1 < M) a1 = *(const uint4*)(A + (size_t)gr1 * K + k0 + lq * 8);
            *(uint4*)&As[lr][lq * 8]      = a0;
            *(uint4*)&As[lr + 64][lq * 8] = a1;
            uint4 b0 = *(const uint4*)(Wt + (size_t)(col0 + lr) * K + k0 + lq * 8);
            uint4 b1 = *(const uint4*)(Wt + (size_t)(col0 + lr + 64) * K + k0 + lq * 8);
            *(uint4*)&Bs[lr][lq * 8]      = b0;
            *(uint4*)&Bs[lr + 64][lq * 8] = b1;
        }
        __syncthreads();
        bf16x8 af[4], bfr[4];
        #pragma unroll
        for (int i = 0; i < 4; i++) af[i]  = *(const bf16x8*)&As[wr + i * 16 + r16][quad * 8];
        #pragma unroll
        for (int j = 0; j < 4; j++) bfr[j] = *(const bf16x8*)&Bs[wc + j * 16 + r16][quad * 8];
        #pragma unroll
        for (int i = 0; i < 4; i++)
            #pragma unroll
            for (int j = 0; j < 4; j++)
                acc[i][j] = __builtin_amdgcn_mfma_f32_16x16x32_bf16(af[i], bfr[j], acc[i][j], 0, 0, 0);
        __syncthreads();
    }

    #pragma unroll
    for (int j = 0; j < 4; j++) {
        int colc = col0 + wc + j * 16 + r16;
        float bval = (MODE == 1) ? bias[colc] : 0.0f;
        #pragma unroll
        for (int i = 0; i < 4; i++) {
            #pragma unroll
            for (int r = 0; r < 4; r++) {
                int row = row0 + wr + i * 16 + quad * 4 + r;
                if (row < M) {
                    float v = acc[i][j][r];
                    if (MODE == 1) v = fmaxf(v + bval, 0.0f);
                    C[(size_t)row * 256 + colc] = f2bf(v);
                }
            }
        }
    }
}

extern "C" void kernel_launch(void* const* d_in, const int* in_sizes, int n_in,
                              void* d_out, int out_size, void* d_ws, size_t ws_size,
                              hipStream_t stream) {
    const float* x   = (const float*)d_in[0];
    const float* W0  = (const float*)d_in[1];
    const float* b0  = (const float*)d_in[2];
    const float* W1  = (const float*)d_in[3];
    const float* b1  = (const float*)d_in[4];
    const float* W2  = (const float*)d_in[5];
    const float* b2  = (const float*)d_in[6];
    const int*   ei  = (const int*)d_in[7];
    const int*   src = ei;
    const int*   dst = ei + NE;
    const int*   batch = (const int*)d_in[8];
    float* out = (float*)d_out;

    char* ws = (char*)d_ws;
    ushort_t* Abf = (ushort_t*)ws;                        // [NN,256] bf16  25.6 MB
    ushort_t* Bbf = (ushort_t*)(ws + 25600000ull);        // [NN,256] bf16  25.6 MB
    ushort_t* xbf = (ushort_t*)(ws + 51200000ull);        // [NN,128] bf16  12.8 MB
    ushort_t* W0t = (ushort_t*)(ws + 64000000ull);        // [256,128] bf16
    ushort_t* W1t = (ushort_t*)(ws + 64065536ull);        // [256,256] bf16
    ushort_t* W2t = (ushort_t*)(ws + 64196608ull);        // [256,256] bf16
    float*    dinv   = (float*)(ws + 64327680ull);        // [NN]
    int*      rowptr = (int*)  (ws + 64527680ull);        // [NN+1]
    int*      cnt    = (int*)  (ws + 64727808ull);        // [NN]
    int*      col    = (int*)  (ws + 64927808ull);        // [NE]
    int*      bsum   = (int*)  (ws + 68127808ull);        // [<=256]

    const int scanBlocks = (NN + 255) / 256;              // 196
    const int aggBlocks256 = (NN + 7) / 8;                // NPW=2, 4 waves
    const int aggBlocks128 = (NN + 15) / 16;              // NPW=4, 4 waves
    const dim3 ggrid((NN + 127) / 128, 2);

    // --- prep converts ---
    conv_x_kernel<<<(NN * CIN / 4 + 255) / 256, 256, 0, stream>>>((const float4*)x, (ushort4*)xbf, NN * CIN / 4);
    conv_wt_kernel<<<(CIN * CH + 255) / 256, 256, 0, stream>>>(W0, W0t, CIN, CH);
    conv_wt_kernel<<<(CH * CH + 255) / 256, 256, 0, stream>>>(W1, W1t, CH, CH);
    conv_wt_kernel<<<(CH * CH + 255) / 256, 256, 0, stream>>>(W2, W2t, CH, CH);

    // --- CSR + normalization ---
    hipMemsetAsync(cnt, 0, (size_t)NN * 4, stream);
    count_kernel<<<(NE + 255) / 256, 256, 0, stream>>>(dst, cnt, NE);
    scan_bsum_kernel<<<scanBlocks, 256, 0, stream>>>(cnt, bsum, NN);
    scan_boff_kernel<<<1, 256, 0, stream>>>(bsum, scanBlocks);
    scan_final_kernel<<<scanBlocks, 256, 0, stream>>>(cnt, bsum, rowptr, dinv, NN);
    hipMemsetAsync(cnt, 0, (size_t)NN * 4, stream);       // reuse as cursor
    scatter_kernel<<<(NE + 255) / 256, 256, 0, stream>>>(src, dst, rowptr, cnt, col, NE);

    // --- layer 0: aggregate x (128 ch), GEMM0 fused bias+relu ---
    node_agg_kernel<CIN, 0, 4><<<aggBlocks128, 256, 0, stream>>>(xbf, rowptr, col, dinv, nullptr, nullptr, Bbf, NN);
    gemm_bf16_kernel<1><<<ggrid, 256, 0, stream>>>(Bbf, W0t, b0, Abf, NN, CIN);

    // --- layer 1: GEMM1 plain, aggregate fused bias+relu ---
    gemm_bf16_kernel<0><<<ggrid, 256, 0, stream>>>(Abf, W1t, nullptr, Bbf, NN, CH);
    node_agg_kernel<CH, 1, 2><<<aggBlocks256, 256, 0, stream>>>(Bbf, rowptr, col, dinv, b1, nullptr, Abf, NN);

    // --- layer 2: GEMM2 plain, aggregate fused bias+relu+pool ---
    gemm_bf16_kernel<0><<<ggrid, 256, 0, stream>>>(Abf, W2t, nullptr, Bbf, NN, CH);
    hipMemsetAsync(out, 0, (size_t)NG * CH * 4, stream);
    node_agg_kernel<CH, 2, 2><<<aggBlocks256, 256, 0, stream>>>(Bbf, rowptr, col, dinv, b2, batch, out, NN);
}

// Round 5
// 549.739 us; speedup vs baseline: 1.4152x; 1.4152x over previous
//
#include <hip/hip_runtime.h>

constexpr int NN  = 50000;   // nodes
constexpr int NE  = 800000;  // edges
constexpr int CIN = 128;     // input channels
constexpr int CH  = 256;     // hidden channels
constexpr int NG  = 512;     // graphs

typedef unsigned short ushort_t;
typedef unsigned int uint_t;

static __device__ __forceinline__ ushort_t f2bf(float f) {
    uint_t u = __float_as_uint(f);
    u += 0x7fffu + ((u >> 16) & 1u);   // round-to-nearest-even
    return (ushort_t)(u >> 16);
}

// ================= prep: fp32 -> bf16 converts =================
__global__ void conv_x_kernel(const float4* __restrict__ x, ushort4* __restrict__ xb, int n4) {
    int i = blockIdx.x * blockDim.x + threadIdx.x;
    if (i >= n4) return;
    float4 v = x[i];
    ushort4 o;
    o.x = f2bf(v.x); o.y = f2bf(v.y); o.z = f2bf(v.z); o.w = f2bf(v.w);
    xb[i] = o;
}

// Wt[n*K + k] = bf16(W[k*N + n])
__global__ void conv_wt_kernel(const float* __restrict__ W, ushort_t* __restrict__ Wt, int K, int N) {
    int i = blockIdx.x * blockDim.x + threadIdx.x;
    if (i >= K * N) return;
    int k = i / N, n = i % N;
    Wt[(size_t)n * K + k] = f2bf(W[i]);
}

// ================= CSR build =================
__global__ void count_kernel(const int* __restrict__ dst, int* __restrict__ cnt, int E) {
    int e = blockIdx.x * blockDim.x + threadIdx.x;
    if (e < E) atomicAdd(&cnt[dst[e]], 1);
}

// hierarchical scan, 3 kernels (256 items per block)
__global__ __launch_bounds__(256) void scan_bsum_kernel(const int* __restrict__ cnt,
                                                        int* __restrict__ bsum, int n) {
    int i = blockIdx.x * 256 + threadIdx.x;
    int v = (i < n) ? cnt[i] : 0;
    #pragma unroll
    for (int off = 32; off >= 1; off >>= 1) v += __shfl_xor(v, off, 64);
    __shared__ int ws[4];
    if ((threadIdx.x & 63) == 0) ws[threadIdx.x >> 6] = v;
    __syncthreads();
    if (threadIdx.x == 0) bsum[blockIdx.x] = ws[0] + ws[1] + ws[2] + ws[3];
}

__global__ __launch_bounds__(256) void scan_boff_kernel(int* __restrict__ bsum, int nb) {
    int tid = threadIdx.x, lane = tid & 63, wid = tid >> 6;
    int v = (tid < nb) ? bsum[tid] : 0;
    int s = v;
    #pragma unroll
    for (int off = 1; off < 64; off <<= 1) {
        int t = __shfl_up(s, off, 64);
        if (lane >= off) s += t;
    }
    __shared__ int wsum[4];
    if (lane == 63) wsum[wid] = s;
    __syncthreads();
    int wadd = 0;
    #pragma unroll
    for (int w = 0; w < 4; w++) if (w < wid) wadd += wsum[w];
    if (tid < nb) bsum[tid] = wadd + s - v;   // exclusive
}

__global__ __launch_bounds__(256) void scan_final_kernel(const int* __restrict__ cnt,
                                                         const int* __restrict__ boff,
                                                         int* __restrict__ rowptr,
                                                         float* __restrict__ dinv, int n) {
    int tid = threadIdx.x, lane = tid & 63, wid = tid >> 6;
    int i = blockIdx.x * 256 + tid;
    int v = (i < n) ? cnt[i] : 0;
    int s = v;
    #pragma unroll
    for (int off = 1; off < 64; off <<= 1) {
        int t = __shfl_up(s, off, 64);
        if (lane >= off) s += t;
    }
    __shared__ int wsum[4];
    if (lane == 63) wsum[wid] = s;
    __syncthreads();
    int wadd = boff[blockIdx.x];
    #pragma unroll
    for (int w = 0; w < 4; w++) if (w < wid) wadd += wsum[w];
    if (i < n) {
        rowptr[i] = wadd + s - v;
        dinv[i]   = rsqrtf((float)v + 1.0f);   // +1 self loop
        if (i == n - 1) rowptr[n] = wadd + s;
    }
}

// scatter: write packed {src, dinv[src]} per CSR slot
__global__ void scatter_kernel(const int* __restrict__ src, const int* __restrict__ dst,
                               const int* __restrict__ rowptr, int* __restrict__ cursor,
                               const float* __restrict__ dinv, int2* __restrict__ epack, int E) {
    int e = blockIdx.x * blockDim.x + threadIdx.x;
    if (e >= E) return;
    int d = dst[e];
    int s = src[e];
    int p = rowptr[d] + atomicAdd(&cursor[d], 1);
    epack[p] = make_int2(s, __float_as_int(dinv[s]));
}

// ================= per-node gather aggregation (bf16) ====
// One wave per node, all 64 lanes on one row; V = C/64 bf16 (8B for C=256).
// 8-deep unroll: 8 independent row loads in flight, chain = epack -> row -> FMA.
// MODE 0: out(bf16) = dd*sum + dd^2*self
// MODE 1: out(bf16) = relu(dd*sum + dd^2*self + bias)
// MODE 2: atomicAdd relu(...) into fp32 out[batch[d]]
template <int C, int MODE>
__global__ __launch_bounds__(256) void node_agg_kernel(
    const ushort_t* __restrict__ h, const int* __restrict__ rowptr,
    const int2* __restrict__ epack, const float* __restrict__ dinv,
    const float* __restrict__ bias, const int* __restrict__ batch,
    void* __restrict__ out_v, int n) {
    constexpr int V = C / 64;                 // bf16 per lane
    int wave = threadIdx.x >> 6;
    int lane = threadIdx.x & 63;
    int d = blockIdx.x * 4 + wave;
    if (d >= n) return;

    int beg = rowptr[d], end = rowptr[d + 1];
    float acc[V] = {};

    for (int e = beg; e < end; e += 8) {
        int   srcs[8];
        float wts[8];
        #pragma unroll
        for (int u = 0; u < 8; u++) {
            int idx = e + u;
            int2 ep = epack[min(idx, NE - 1)];
            bool a = idx < end;               // wave-uniform
            srcs[u] = a ? ep.x : d;
            wts[u]  = a ? __int_as_float(ep.y) : 0.0f;
        }
        if constexpr (V == 4) {
            uint2 rv[8];
            #pragma unroll
            for (int u = 0; u < 8; u++)
                rv[u] = *(const uint2*)(h + (size_t)srcs[u] * C + lane * 4);
            #pragma unroll
            for (int u = 0; u < 8; u++) {
                float w = wts[u];
                acc[0] += w * __uint_as_float(rv[u].x << 16);
                acc[1] += w * __uint_as_float(rv[u].x & 0xffff0000u);
                acc[2] += w * __uint_as_float(rv[u].y << 16);
                acc[3] += w * __uint_as_float(rv[u].y & 0xffff0000u);
            }
        } else {
            uint_t rv[8];
            #pragma unroll
            for (int u = 0; u < 8; u++)
                rv[u] = *(const uint_t*)(h + (size_t)srcs[u] * C + lane * 2);
            #pragma unroll
            for (int u = 0; u < 8; u++) {
                float w = wts[u];
                acc[0] += w * __uint_as_float(rv[u] << 16);
                acc[1] += w * __uint_as_float(rv[u] & 0xffff0000u);
            }
        }
    }

    float dd = dinv[d];
    float self[V];
    if constexpr (V == 4) {
        uint2 sv = *(const uint2*)(h + (size_t)d * C + lane * 4);
        self[0] = __uint_as_float(sv.x << 16);
        self[1] = __uint_as_float(sv.x & 0xffff0000u);
        self[2] = __uint_as_float(sv.y << 16);
        self[3] = __uint_as_float(sv.y & 0xffff0000u);
    } else {
        uint_t sv = *(const uint_t*)(h + (size_t)d * C + lane * 2);
        self[0] = __uint_as_float(sv << 16);
        self[1] = __uint_as_float(sv & 0xffff0000u);
    }

    float r[V];
    #pragma unroll
    for (int i = 0; i < V; i++) {
        float v = dd * acc[i] + dd * dd * self[i];
        if constexpr (MODE >= 1) v = fmaxf(v + bias[lane * V + i], 0.0f);
        r[i] = v;
    }

    if constexpr (MODE == 2) {
        float* o = (float*)out_v + (size_t)batch[d] * C + lane * V;
        #pragma unroll
        for (int i = 0; i < V; i++) atomicAdd(o + i, r[i]);
    } else if constexpr (V == 4) {
        uint2 o;
        o.x = (uint_t)f2bf(r[0]) | ((uint_t)f2bf(r[1]) << 16);
        o.y = (uint_t)f2bf(r[2]) | ((uint_t)f2bf(r[3]) << 16);
        *(uint2*)((ushort_t*)out_v + (size_t)d * C + lane * 4) = o;
    } else {
        uint_t o = (uint_t)f2bf(r[0]) | ((uint_t)f2bf(r[1]) << 16);
        *(uint_t*)((ushort_t*)out_v + (size_t)d * C + lane * 2) = o;
    }
}

// ================= bf16 MFMA GEMM: C[M,256] = A[M,K] @ Wt[N,K]^T =================
typedef __attribute__((ext_vector_type(8))) short bf16x8;
typedef __attribute__((ext_vector_type(4))) float f32x4;

template <int MODE>
__global__ __launch_bounds__(256) void gemm_bf16_kernel(
    const ushort_t* __restrict__ A, const ushort_t* __restrict__ Wt,
    const float* __restrict__ bias, ushort_t* __restrict__ C, int M, int K) {
    __shared__ ushort_t As[128][40];
    __shared__ ushort_t Bs[128][40];
    int tid = threadIdx.x;
    int row0 = blockIdx.x * 128, col0 = blockIdx.y * 128;
    int lr = tid >> 2, lq = tid & 3;
    int lane = tid & 63, wv = tid >> 6;
    int wr = (wv >> 1) * 64, wc = (wv & 1) * 64;
    int r16 = lane & 15, quad = lane >> 4;

    f32x4 acc[4][4] = {};

    for (int k0 = 0; k0 < K; k0 += 32) {
        {
            int gr0 = row0 + lr, gr1 = row0 + lr + 64;
            uint4 a0 = make_uint4(0, 0, 0, 0), a1 = make_uint4(0, 0, 0, 0);
            if (gr0 < M) a0 = *(const uint4*)(A + (size_t)gr0 * K + k0 + lq * 8);
            if (gr1 < M) a1 = *(const uint4*)(A + (size_t)gr1 * K + k0 + lq * 8);
            *(uint4*)&As[lr][lq * 8]      = a0;
            *(uint4*)&As[lr + 64][lq * 8] = a1;
            uint4 b0 = *(const uint4*)(Wt + (size_t)(col0 + lr) * K + k0 + lq * 8);
            uint4 b1 = *(const uint4*)(Wt + (size_t)(col0 + lr + 64) * K + k0 + lq * 8);
            *(uint4*)&Bs[lr][lq * 8]      = b0;
            *(uint4*)&Bs[lr + 64][lq * 8] = b1;
        }
        __syncthreads();
        bf16x8 af[4], bfr[4];
        #pragma unroll
        for (int i = 0; i < 4; i++) af[i]  = *(const bf16x8*)&As[wr + i * 16 + r16][quad * 8];
        #pragma unroll
        for (int j = 0; j < 4; j++) bfr[j] = *(const bf16x8*)&Bs[wc + j * 16 + r16][quad * 8];
        #pragma unroll
        for (int i = 0; i < 4; i++)
            #pragma unroll
            for (int j = 0; j < 4; j++)
                acc[i][j] = __builtin_amdgcn_mfma_f32_16x16x32_bf16(af[i], bfr[j], acc[i][j], 0, 0, 0);
        __syncthreads();
    }

    #pragma unroll
    for (int j = 0; j < 4; j++) {
        int colc = col0 + wc + j * 16 + r16;
        float bval = (MODE == 1) ? bias[colc] : 0.0f;
        #pragma unroll
        for (int i = 0; i < 4; i++) {
            #pragma unroll
            for (int r = 0; r < 4; r++) {
                int row = row0 + wr + i * 16 + quad * 4 + r;
                if (row < M) {
                    float v = acc[i][j][r];
                    if (MODE == 1) v = fmaxf(v + bval, 0.0f);
                    C[(size_t)row * 256 + colc] = f2bf(v);
                }
            }
        }
    }
}

extern "C" void kernel_launch(void* const* d_in, const int* in_sizes, int n_in,
                              void* d_out, int out_size, void* d_ws, size_t ws_size,
                              hipStream_t stream) {
    const float* x   = (const float*)d_in[0];
    const float* W0  = (const float*)d_in[1];
    const float* b0  = (const float*)d_in[2];
    const float* W1  = (const float*)d_in[3];
    const float* b1  = (const float*)d_in[4];
    const float* W2  = (const float*)d_in[5];
    const float* b2  = (const float*)d_in[6];
    const int*   ei  = (const int*)d_in[7];
    const int*   src = ei;
    const int*   dst = ei + NE;
    const int*   batch = (const int*)d_in[8];
    float* out = (float*)d_out;

    char* ws = (char*)d_ws;
    ushort_t* Abf = (ushort_t*)ws;                        // [NN,256] bf16  25.6 MB
    ushort_t* Bbf = (ushort_t*)(ws + 25600000ull);        // [NN,256] bf16  25.6 MB
    ushort_t* xbf = (ushort_t*)(ws + 51200000ull);        // [NN,128] bf16  12.8 MB
    ushort_t* W0t = (ushort_t*)(ws + 64000000ull);        // [256,128] bf16
    ushort_t* W1t = (ushort_t*)(ws + 64065536ull);        // [256,256] bf16
    ushort_t* W2t = (ushort_t*)(ws + 64196608ull);        // [256,256] bf16
    float*    dinv   = (float*)(ws + 64327680ull);        // [NN]
    int*      rowptr = (int*)  (ws + 64527680ull);        // [NN+1]
    int*      cnt    = (int*)  (ws + 64727808ull);        // [NN]
    int2*     epack  = (int2*) (ws + 64927808ull);        // [NE] {src, dinv[src]} 6.4 MB
    int*      bsum   = (int*)  (ws + 71327808ull);        // [<=256]

    const int scanBlocks = (NN + 255) / 256;              // 196
    const int nodeBlocks = (NN + 3) / 4;                  // 1 node per wave, 4 waves/block
    const dim3 ggrid((NN + 127) / 128, 2);

    // --- prep converts ---
    conv_x_kernel<<<(NN * CIN / 4 + 255) / 256, 256, 0, stream>>>((const float4*)x, (ushort4*)xbf, NN * CIN / 4);
    conv_wt_kernel<<<(CIN * CH + 255) / 256, 256, 0, stream>>>(W0, W0t, CIN, CH);
    conv_wt_kernel<<<(CH * CH + 255) / 256, 256, 0, stream>>>(W1, W1t, CH, CH);
    conv_wt_kernel<<<(CH * CH + 255) / 256, 256, 0, stream>>>(W2, W2t, CH, CH);

    // --- CSR + normalization ---
    hipMemsetAsync(cnt, 0, (size_t)NN * 4, stream);
    count_kernel<<<(NE + 255) / 256, 256, 0, stream>>>(dst, cnt, NE);
    scan_bsum_kernel<<<scanBlocks, 256, 0, stream>>>(cnt, bsum, NN);
    scan_boff_kernel<<<1, 256, 0, stream>>>(bsum, scanBlocks);
    scan_final_kernel<<<scanBlocks, 256, 0, stream>>>(cnt, bsum, rowptr, dinv, NN);
    hipMemsetAsync(cnt, 0, (size_t)NN * 4, stream);       // reuse as cursor
    scatter_kernel<<<(NE + 255) / 256, 256, 0, stream>>>(src, dst, rowptr, cnt, dinv, epack, NE);

    // --- layer 0: aggregate x (128 ch), GEMM0 fused bias+relu ---
    node_agg_kernel<CIN, 0><<<nodeBlocks, 256, 0, stream>>>(xbf, rowptr, epack, dinv, nullptr, nullptr, Bbf, NN);
    gemm_bf16_kernel<1><<<ggrid, 256, 0, stream>>>(Bbf, W0t, b0, Abf, NN, CIN);

    // --- layer 1: GEMM1 plain, aggregate fused bias+relu ---
    gemm_bf16_kernel<0><<<ggrid, 256, 0, stream>>>(Abf, W1t, nullptr, Bbf, NN, CH);
    node_agg_kernel<CH, 1><<<nodeBlocks, 256, 0, stream>>>(Bbf, rowptr, epack, dinv, b1, nullptr, Abf, NN);

    // --- layer 2: GEMM2 plain, aggregate fused bias+relu+pool ---
    gemm_bf16_kernel<0><<<ggrid, 256, 0, stream>>>(Abf, W2t, nullptr, Bbf, NN, CH);
    hipMemsetAsync(out, 0, (size_t)NG * CH * 4, stream);
    node_agg_kernel<CH, 2><<<nodeBlocks, 256, 0, stream>>>(Bbf, rowptr, epack, dinv, b2, batch, out, NN);
}